// Round 17
// baseline (270.786 us; speedup 1.0000x reference)
//
#include <hip/hip_runtime.h>

// BiGRU, B=512, T=512, D=16, H=64.
// Backward direction needs only ONE cell step (ys_b[0] = GRUCell(x[:,T-1,:], 0)).
//
// Round-18: R16 structure (same-SIMD consumer pair; all-pk_fma_f16 MACs)
// + exp2-domain folding.
//  R16's 205us came from a visibly sick container (pytest 87s, rocprof 115s,
//  degraded counters) -- consistent with ~13% downclock of R14's 183.7, so
//  n-pk is retained. This round additionally folds the exp scale constants
//  into weights/biases AT LOAD:
//   - r,z: scale by -log2e (negation folded too): sigmoid = rcp(1+2^(a'))
//     with a' = pg + s directly.  n: scale by +2*log2e: tanh = 1-2*rcp(2^b'+1).
//   - v_exp_f32 IS 2^x: saves 3 v_mul + 2 negates per step, on the chain.
//  Producers store pre-scaled pre-activations (scaling folded into their
//  f32 weights/biases at load, zero per-step cost). Backward tail unchanged.
//  Refutation: if >=200us with HEALTHY infra, revert to exact R14 (183.7).

#define Hh 64
#define Dd 16
#define Tt 512
#define Bb 512
#define CH 16
#define NC (Tt / CH)        // 32 chunks
#define BUFSZ (CH * Hh)     // 1024 float4 per buffer
#define LOG2E 1.44269504088896f

typedef _Float16 half2v __attribute__((ext_vector_type(2)));

__device__ __forceinline__ float rcp_fast(float v) { return __builtin_amdgcn_rcpf(v); }
__device__ __forceinline__ float ex2(float x) {
    float r; asm("v_exp_f32 %0, %1" : "=v"(r) : "v"(x)); return r;
}
// tail-only (original domain)
__device__ __forceinline__ float sigmoid_fast(float v) {
    return rcp_fast(1.0f + __expf(-v));
}
__device__ __forceinline__ float tanh_fast(float v) {
    return 1.0f - 2.0f * rcp_fast(__expf(2.0f * v) + 1.0f);
}
__device__ __forceinline__ float dot4(float4 a, float4 b) {
    return a.x * b.x + a.y * b.y + a.z * b.z + a.w * b.w;
}
__device__ __forceinline__ void pkfma16(half2v& a, half2v b, half2v c) {
    asm("v_pk_fma_f16 %0, %1, %2, %0" : "+v"(a) : "v"(b), "v"(c));
}
__device__ __forceinline__ half2v bc_h2(float f) {
    union { float f; half2v h; } u; u.f = f; return u.h;
}
__device__ __forceinline__ void lds_barrier() {
    asm volatile("s_waitcnt lgkmcnt(0)\n\ts_barrier" ::: "memory");
}

// One broadcast float4 U (h pairs 4P..4P+3 = 8 f16 h values): 12 pk_fma_f16.
#define MIX(U, P)                                                            \
    {                                                                        \
        const half2v p0_ = bc_h2(U.x), p1_ = bc_h2(U.y);                     \
        const half2v p2_ = bc_h2(U.z), p3_ = bc_h2(U.w);                     \
        pkfma16(ra0, wrh[4*(P)+0], p0_);                                     \
        pkfma16(za0, wzh[4*(P)+0], p0_);                                     \
        pkfma16(na0, wnh[4*(P)+0], p0_);                                     \
        pkfma16(ra1, wrh[4*(P)+1], p1_);                                     \
        pkfma16(za1, wzh[4*(P)+1], p1_);                                     \
        pkfma16(na1, wnh[4*(P)+1], p1_);                                     \
        pkfma16(ra0, wrh[4*(P)+2], p2_);                                     \
        pkfma16(za0, wzh[4*(P)+2], p2_);                                     \
        pkfma16(na0, wnh[4*(P)+2], p2_);                                     \
        pkfma16(ra1, wrh[4*(P)+3], p3_);                                     \
        pkfma16(za1, wzh[4*(P)+3], p3_);                                     \
        pkfma16(na1, wnh[4*(P)+3], p3_);                                     \
    }

// One recurrence step, T compile-time. pg/{weights} are in the FOLDED domain:
//  pg.x, pg.y, sr, sz pre-scaled by -log2e;  pg.z, bhnr, sn by +2*log2e.
#define STEPT(T) do {                                                        \
    hbuf16[j] = (_Float16)h;             /* publish h (in-order DS pipe) */  \
    const float4* hq = (const float4*)hbuf16;      /* wave-uniform addr  */  \
    float4 u0 = hq[0], u1 = hq[1], u2 = hq[2], u3 = hq[3];                   \
    float4 u4 = hq[4], u5 = hq[5], u6 = hq[6], u7 = hq[7];                   \
    const float4 ng = base[(((T) + 1) & (CH - 1)) * Hh];                     \
    half2v ra0 = {0,0}, ra1 = {0,0}, za0 = {0,0}, za1 = {0,0};               \
    half2v na0 = {0,0}, na1 = {0,0};                                         \
    MIX(u0, 0) MIX(u1, 1) MIX(u2, 2) MIX(u3, 3)                              \
    MIX(u4, 4) MIX(u5, 5) MIX(u6, 6) MIX(u7, 7)                              \
    const half2v rs = ra0 + ra1;                                             \
    const half2v zs = za0 + za1;                                             \
    const half2v ns = na0 + na1;                                             \
    const float sr = (float)rs.x + (float)rs.y;                              \
    const float sz = (float)zs.x + (float)zs.y;                              \
    const float sn = (float)ns.x + (float)ns.y;                              \
    const float r = rcp_fast(1.0f + ex2(pg.x + sr));                         \
    const float z = rcp_fast(1.0f + ex2(pg.y + sz));                         \
    const float n = fmaf(-2.0f, rcp_fast(ex2(pg.z + r * (bhnr + sn)) + 1.0f), 1.0f); \
    h = n + z * (h - n);                                                     \
    pg = ng;                                                                 \
} while (0)

__global__ __launch_bounds__(256, 2)
void bigru_pc_kernel(const float* __restrict__ x,
                     const float* __restrict__ w_ih_f, const float* __restrict__ w_hh_f,
                     const float* __restrict__ b_ih_f, const float* __restrict__ b_hh_f,
                     const float* __restrict__ w_ih_b, const float* __restrict__ w_hh_b,
                     const float* __restrict__ b_ih_b, const float* __restrict__ b_hh_b,
                     const float* __restrict__ fc_w,  const float* __restrict__ fc_b,
                     float* __restrict__ out)
{
    const int tid  = threadIdx.x;
    const int j    = tid & 63;          // hidden unit
    const int w    = tid >> 6;          // wave 0..3
    const int b    = blockIdx.x;        // batch element
    // cons = b&3: co-resident blocks (b, b+256) put their consumers on the
    // SAME SIMD -> the two serial chains latency-hide each other (R14/R15
    // A/B: same-SIMD 183.7us, spread 309us).
    const int cons = b & 3;

    __shared__ __align__(16) float4    xgs4[2 * BUFSZ];  // 32 KB packed gate preacts
    __shared__ __align__(16) _Float16  hbuf16[Hh];       // 128 B f16 h broadcast

    const float* xrow = x + (size_t)b * Tt * Dd;

    if (w == cons) {
        // ===================== CONSUMER: the recurrence =====================
        __builtin_amdgcn_s_setprio(1);   // win SIMD arbitration vs producers
        // W_hh rows {j,64+j,128+j} as f16 pairs, pre-scaled into the exp2
        // domain: r,z rows by -log2e; n row by +2*log2e. 96 VGPRs total.
        half2v wrh[Hh/2], wzh[Hh/2], wnh[Hh/2];
        {
            const float s1 = -LOG2E, s2 = 2.0f * LOG2E;
            const float4* r0 = (const float4*)(w_hh_f + (size_t)j            * Hh);
            const float4* r1 = (const float4*)(w_hh_f + (size_t)(Hh + j)     * Hh);
            const float4* r2 = (const float4*)(w_hh_f + (size_t)(2 * Hh + j) * Hh);
#pragma unroll
            for (int q = 0; q < Hh / 4; ++q) {
                float4 a = r0[q];
                wrh[2*q]   = (half2v){(_Float16)(a.x*s1), (_Float16)(a.y*s1)};
                wrh[2*q+1] = (half2v){(_Float16)(a.z*s1), (_Float16)(a.w*s1)};
                float4 c = r1[q];
                wzh[2*q]   = (half2v){(_Float16)(c.x*s1), (_Float16)(c.y*s1)};
                wzh[2*q+1] = (half2v){(_Float16)(c.z*s1), (_Float16)(c.w*s1)};
                float4 e = r2[q];
                wnh[2*q]   = (half2v){(_Float16)(e.x*s2), (_Float16)(e.y*s2)};
                wnh[2*q+1] = (half2v){(_Float16)(e.z*s2), (_Float16)(e.w*s2)};
            }
        }
        const float bhnr = b_hh_f[2 * Hh + j] * (2.0f * LOG2E);
        float h = 0.0f;

        for (int c = 0; c < NC; ++c) {
            lds_barrier();                       // chunk c ready in buf[c&1]
            const float4* base = xgs4 + (c & 1) * BUFSZ + j;
            float4 pg = base[0];                 // {ar', az', an', -} for t=0
            STEPT(0);  STEPT(1);  STEPT(2);  STEPT(3);
            STEPT(4);  STEPT(5);  STEPT(6);  STEPT(7);
            STEPT(8);  STEPT(9);  STEPT(10); STEPT(11);
            STEPT(12); STEPT(13); STEPT(14); STEPT(15);
        }

        // ---- tail: backward single cell step + FC (all f32, unscaled) ----
        float ar   = b_ih_b[j]          + b_hh_b[j];
        float az   = b_ih_b[Hh + j]     + b_hh_b[Hh + j];
        float axn  = b_ih_b[2 * Hh + j];
        const float bhnb = b_hh_b[2 * Hh + j];
        {
            const float4* xl = (const float4*)(xrow + (size_t)(Tt - 1) * Dd);
            float4 xv0 = xl[0], xv1 = xl[1], xv2 = xl[2], xv3 = xl[3];
            const float4* q0 = (const float4*)(w_ih_b + (size_t)j            * Dd);
            const float4* q1 = (const float4*)(w_ih_b + (size_t)(Hh + j)     * Dd);
            const float4* q2 = (const float4*)(w_ih_b + (size_t)(2 * Hh + j) * Dd);
            ar  += dot4(q0[0], xv0) + dot4(q0[1], xv1) + dot4(q0[2], xv2) + dot4(q0[3], xv3);
            az  += dot4(q1[0], xv0) + dot4(q1[1], xv1) + dot4(q1[2], xv2) + dot4(q1[3], xv3);
            axn += dot4(q2[0], xv0) + dot4(q2[1], xv1) + dot4(q2[2], xv2) + dot4(q2[3], xv3);
        }
        const float rb = sigmoid_fast(ar);
        const float zb = sigmoid_fast(az);
        const float nb = tanh_fast(axn + rb * bhnb);
        const float hb = (1.0f - zb) * nb;   // h0 = 0

        float v = fc_w[j] * h + fc_w[Hh + j] * hb;
#pragma unroll
        for (int off = 32; off > 0; off >>= 1)
            v += __shfl_xor(v, off, 64);
        if (j == 0) out[b] = v + fc_b[0];
    } else {
        // ==== PRODUCERS: input projections, pre-scaled into exp2 domain ====
        const int pw = (w > cons) ? (w - 1) : w;   // 0..2
        float4 wir[4], wiz[4], win[4];
        {
            const float s1 = -LOG2E, s2 = 2.0f * LOG2E;
            const float4* p0 = (const float4*)(w_ih_f + (size_t)j            * Dd);
            const float4* p1 = (const float4*)(w_ih_f + (size_t)(Hh + j)     * Dd);
            const float4* p2 = (const float4*)(w_ih_f + (size_t)(2 * Hh + j) * Dd);
#pragma unroll
            for (int q = 0; q < 4; ++q) {
                float4 a = p0[q]; wir[q] = make_float4(a.x*s1, a.y*s1, a.z*s1, a.w*s1);
                float4 c = p1[q]; wiz[q] = make_float4(c.x*s1, c.y*s1, c.z*s1, c.w*s1);
                float4 e = p2[q]; win[q] = make_float4(e.x*s2, e.y*s2, e.z*s2, e.w*s2);
            }
        }
        const float bxr = (b_ih_f[j]          + b_hh_f[j])      * (-LOG2E);
        const float bxz = (b_ih_f[Hh + j]     + b_hh_f[Hh + j]) * (-LOG2E);
        const float bxn = b_ih_f[2 * Hh + j]                    * (2.0f * LOG2E);

#define PRODUCE(C1) {                                                        \
            float4* obase = xgs4 + ((C1) & 1) * BUFSZ + j;                   \
            for (int tt = pw; tt < CH; tt += 3) {                            \
                const float4* xq = (const float4*)(xrow + (size_t)((C1) * CH + tt) * Dd); \
                float4 x0 = xq[0], x1 = xq[1], x2 = xq[2], x3 = xq[3];       \
                float ar_ = bxr + dot4(wir[0],x0) + dot4(wir[1],x1)          \
                                + dot4(wir[2],x2) + dot4(wir[3],x3);         \
                float az_ = bxz + dot4(wiz[0],x0) + dot4(wiz[1],x1)          \
                                + dot4(wiz[2],x2) + dot4(wiz[3],x3);         \
                float an_ = bxn + dot4(win[0],x0) + dot4(win[1],x1)          \
                                + dot4(win[2],x2) + dot4(win[3],x3);         \
                obase[tt * Hh] = make_float4(ar_, az_, an_, 0.0f);           \
            }                                                                \
        }

        PRODUCE(0);                       // chunk 0 before the first barrier
        for (int c = 0; c < NC; ++c) {
            lds_barrier();                // publish chunk c / consumer enters
            if (c + 1 < NC) PRODUCE(c + 1);  // fill other buffer during chunk c
        }
#undef PRODUCE
    }
}

extern "C" void kernel_launch(void* const* d_in, const int* in_sizes, int n_in,
                              void* d_out, int out_size, void* d_ws, size_t ws_size,
                              hipStream_t stream) {
    const float* x      = (const float*)d_in[0];
    const float* w_ih_f = (const float*)d_in[1];
    const float* w_hh_f = (const float*)d_in[2];
    const float* b_ih_f = (const float*)d_in[3];
    const float* b_hh_f = (const float*)d_in[4];
    const float* w_ih_b = (const float*)d_in[5];
    const float* w_hh_b = (const float*)d_in[6];
    const float* b_ih_b = (const float*)d_in[7];
    const float* b_hh_b = (const float*)d_in[8];
    const float* fc_w   = (const float*)d_in[9];
    const float* fc_b   = (const float*)d_in[10];

    bigru_pc_kernel<<<dim3(Bb), dim3(256), 0, stream>>>(
        x, w_ih_f, w_hh_f, b_ih_f, b_hh_f,
        w_ih_b, w_hh_b, b_ih_b, b_hh_b, fc_w, fc_b,
        (float*)d_out);
}

// Round 18
// 241.881 us; speedup vs baseline: 1.1195x; 1.1195x over previous
//
#include <hip/hip_runtime.h>

// BiGRU, B=512, T=512, D=16, H=64.
// Backward direction needs only ONE cell step (ys_b[0] = GRUCell(x[:,T-1,:], 0)).
//
// Round-19: controlled A/B vs R14 (best verified, 183.7us prof).
//  R17 (healthy infra) = 209us bundled {n-gate pk_fma_f16, exp2 fold} vs R14.
//  The fold removes instructions and cannot cost +25us; suspect is n-pk
//  (dot2's issue slot pattern helped the co-resident consumer pair, and/or
//  the extra f16->f32 epilogue conversions sit on the serial chain).
//  THIS ROUND: exact R14 MIX (r,z via pk_fma_f16 with f16 accum; n via
//  v_dot2_f32_f16 with F32 accum) + ONLY the exp2-domain fold as delta:
//   - r,z weights/biases/preacts scaled by -log2e; n path by +2*log2e
//     (folded at load / in producers, zero per-step cost).
//   - gates use raw v_exp_f32 (= 2^x): saves 3 v_mul + negates per step.
//  Outcome reads: ~178 -> fold good, n-pk was the regression (bank this);
//  ~184 -> fold neutral (R14 is floor); >=190 -> revert to exact R14 final.

#define Hh 64
#define Dd 16
#define Tt 512
#define Bb 512
#define CH 16
#define NC (Tt / CH)        // 32 chunks
#define BUFSZ (CH * Hh)     // 1024 float4 per buffer
#define LOG2E 1.44269504088896f

typedef _Float16 half2v __attribute__((ext_vector_type(2)));

__device__ __forceinline__ float rcp_fast(float v) { return __builtin_amdgcn_rcpf(v); }
__device__ __forceinline__ float ex2(float x) {
    float r; asm("v_exp_f32 %0, %1" : "=v"(r) : "v"(x)); return r;
}
// tail-only (original domain)
__device__ __forceinline__ float sigmoid_fast(float v) {
    return rcp_fast(1.0f + __expf(-v));
}
__device__ __forceinline__ float tanh_fast(float v) {
    return 1.0f - 2.0f * rcp_fast(__expf(2.0f * v) + 1.0f);
}
__device__ __forceinline__ float dot4(float4 a, float4 b) {
    return a.x * b.x + a.y * b.y + a.z * b.z + a.w * b.w;
}
__device__ __forceinline__ float fd2(half2v a, half2v b, float c) {
    return __builtin_amdgcn_fdot2(a, b, c, false);
}
__device__ __forceinline__ void pkfma16(half2v& a, half2v b, half2v c) {
    asm("v_pk_fma_f16 %0, %1, %2, %0" : "+v"(a) : "v"(b), "v"(c));
}
__device__ __forceinline__ half2v bc_h2(float f) {
    union { float f; half2v h; } u; u.f = f; return u.h;
}
__device__ __forceinline__ void lds_barrier() {
    asm volatile("s_waitcnt lgkmcnt(0)\n\ts_barrier" ::: "memory");
}

// EXACT R14 MIX: r,z -> 8 pk_fma_f16 (f16 accum); n -> 4 dot2 (f32 accum).
#define MIX(U, P)                                                            \
    {                                                                        \
        const half2v p0_ = bc_h2(U.x), p1_ = bc_h2(U.y);                     \
        const half2v p2_ = bc_h2(U.z), p3_ = bc_h2(U.w);                     \
        pkfma16(ra0, wrh[4*(P)+0], p0_);                                     \
        pkfma16(za0, wzh[4*(P)+0], p0_);                                     \
        sn0 = fd2(wnh[4*(P)+0], p0_, sn0);                                   \
        pkfma16(ra1, wrh[4*(P)+1], p1_);                                     \
        pkfma16(za1, wzh[4*(P)+1], p1_);                                     \
        sn1 = fd2(wnh[4*(P)+1], p1_, sn1);                                   \
        pkfma16(ra0, wrh[4*(P)+2], p2_);                                     \
        pkfma16(za0, wzh[4*(P)+2], p2_);                                     \
        sn0 = fd2(wnh[4*(P)+2], p2_, sn0);                                   \
        pkfma16(ra1, wrh[4*(P)+3], p3_);                                     \
        pkfma16(za1, wzh[4*(P)+3], p3_);                                     \
        sn1 = fd2(wnh[4*(P)+3], p3_, sn1);                                   \
    }

// One recurrence step, T compile-time. Folded domain:
//  pg.x, pg.y, sr, sz pre-scaled by -log2e;  pg.z, bhnr, sn by +2*log2e.
#define STEPT(T) do {                                                        \
    hbuf16[j] = (_Float16)h;             /* publish h (in-order DS pipe) */  \
    const float4* hq = (const float4*)hbuf16;      /* wave-uniform addr  */  \
    float4 u0 = hq[0], u1 = hq[1], u2 = hq[2], u3 = hq[3];                   \
    float4 u4 = hq[4], u5 = hq[5], u6 = hq[6], u7 = hq[7];                   \
    const float4 ng = base[(((T) + 1) & (CH - 1)) * Hh];                     \
    half2v ra0 = {0,0}, ra1 = {0,0}, za0 = {0,0}, za1 = {0,0};               \
    float sn0 = 0.f, sn1 = 0.f;                                              \
    MIX(u0, 0) MIX(u1, 1) MIX(u2, 2) MIX(u3, 3)                              \
    MIX(u4, 4) MIX(u5, 5) MIX(u6, 6) MIX(u7, 7)                              \
    const half2v rs = ra0 + ra1;                                             \
    const half2v zs = za0 + za1;                                             \
    const float sr = (float)rs.x + (float)rs.y;                              \
    const float sz = (float)zs.x + (float)zs.y;                              \
    const float sn = sn0 + sn1;                                              \
    const float r = rcp_fast(1.0f + ex2(pg.x + sr));                         \
    const float z = rcp_fast(1.0f + ex2(pg.y + sz));                         \
    const float n = fmaf(-2.0f, rcp_fast(ex2(pg.z + r * (bhnr + sn)) + 1.0f), 1.0f); \
    h = n + z * (h - n);                                                     \
    pg = ng;                                                                 \
} while (0)

__global__ __launch_bounds__(256, 2)
void bigru_pc_kernel(const float* __restrict__ x,
                     const float* __restrict__ w_ih_f, const float* __restrict__ w_hh_f,
                     const float* __restrict__ b_ih_f, const float* __restrict__ b_hh_f,
                     const float* __restrict__ w_ih_b, const float* __restrict__ w_hh_b,
                     const float* __restrict__ b_ih_b, const float* __restrict__ b_hh_b,
                     const float* __restrict__ fc_w,  const float* __restrict__ fc_b,
                     float* __restrict__ out)
{
    const int tid  = threadIdx.x;
    const int j    = tid & 63;          // hidden unit
    const int w    = tid >> 6;          // wave 0..3
    const int b    = blockIdx.x;        // batch element
    // cons = b&3: co-resident blocks (b, b+256) put their consumers on the
    // SAME SIMD -> the two serial chains latency-hide each other (R14/R15
    // A/B: same-SIMD 183.7us, spread 309us).
    const int cons = b & 3;

    __shared__ __align__(16) float4    xgs4[2 * BUFSZ];  // 32 KB packed gate preacts
    __shared__ __align__(16) _Float16  hbuf16[Hh];       // 128 B f16 h broadcast

    const float* xrow = x + (size_t)b * Tt * Dd;

    if (w == cons) {
        // ===================== CONSUMER: the recurrence =====================
        __builtin_amdgcn_s_setprio(1);   // win SIMD arbitration vs producers
        // W_hh rows {j,64+j,128+j} as f16 pairs, pre-scaled into the exp2
        // domain: r,z rows by -log2e; n row by +2*log2e. 96 VGPRs total.
        half2v wrh[Hh/2], wzh[Hh/2], wnh[Hh/2];
        {
            const float s1 = -LOG2E, s2 = 2.0f * LOG2E;
            const float4* r0 = (const float4*)(w_hh_f + (size_t)j            * Hh);
            const float4* r1 = (const float4*)(w_hh_f + (size_t)(Hh + j)     * Hh);
            const float4* r2 = (const float4*)(w_hh_f + (size_t)(2 * Hh + j) * Hh);
#pragma unroll
            for (int q = 0; q < Hh / 4; ++q) {
                float4 a = r0[q];
                wrh[2*q]   = (half2v){(_Float16)(a.x*s1), (_Float16)(a.y*s1)};
                wrh[2*q+1] = (half2v){(_Float16)(a.z*s1), (_Float16)(a.w*s1)};
                float4 c = r1[q];
                wzh[2*q]   = (half2v){(_Float16)(c.x*s1), (_Float16)(c.y*s1)};
                wzh[2*q+1] = (half2v){(_Float16)(c.z*s1), (_Float16)(c.w*s1)};
                float4 e = r2[q];
                wnh[2*q]   = (half2v){(_Float16)(e.x*s2), (_Float16)(e.y*s2)};
                wnh[2*q+1] = (half2v){(_Float16)(e.z*s2), (_Float16)(e.w*s2)};
            }
        }
        const float bhnr = b_hh_f[2 * Hh + j] * (2.0f * LOG2E);
        float h = 0.0f;

        for (int c = 0; c < NC; ++c) {
            lds_barrier();                       // chunk c ready in buf[c&1]
            const float4* base = xgs4 + (c & 1) * BUFSZ + j;
            float4 pg = base[0];                 // {ar', az', an', -} for t=0
            STEPT(0);  STEPT(1);  STEPT(2);  STEPT(3);
            STEPT(4);  STEPT(5);  STEPT(6);  STEPT(7);
            STEPT(8);  STEPT(9);  STEPT(10); STEPT(11);
            STEPT(12); STEPT(13); STEPT(14); STEPT(15);
        }

        // ---- tail: backward single cell step + FC (all f32, unscaled) ----
        float ar   = b_ih_b[j]          + b_hh_b[j];
        float az   = b_ih_b[Hh + j]     + b_hh_b[Hh + j];
        float axn  = b_ih_b[2 * Hh + j];
        const float bhnb = b_hh_b[2 * Hh + j];
        {
            const float4* xl = (const float4*)(xrow + (size_t)(Tt - 1) * Dd);
            float4 xv0 = xl[0], xv1 = xl[1], xv2 = xl[2], xv3 = xl[3];
            const float4* q0 = (const float4*)(w_ih_b + (size_t)j            * Dd);
            const float4* q1 = (const float4*)(w_ih_b + (size_t)(Hh + j)     * Dd);
            const float4* q2 = (const float4*)(w_ih_b + (size_t)(2 * Hh + j) * Dd);
            ar  += dot4(q0[0], xv0) + dot4(q0[1], xv1) + dot4(q0[2], xv2) + dot4(q0[3], xv3);
            az  += dot4(q1[0], xv0) + dot4(q1[1], xv1) + dot4(q1[2], xv2) + dot4(q1[3], xv3);
            axn += dot4(q2[0], xv0) + dot4(q2[1], xv1) + dot4(q2[2], xv2) + dot4(q2[3], xv3);
        }
        const float rb = sigmoid_fast(ar);
        const float zb = sigmoid_fast(az);
        const float nb = tanh_fast(axn + rb * bhnb);
        const float hb = (1.0f - zb) * nb;   // h0 = 0

        float v = fc_w[j] * h + fc_w[Hh + j] * hb;
#pragma unroll
        for (int off = 32; off > 0; off >>= 1)
            v += __shfl_xor(v, off, 64);
        if (j == 0) out[b] = v + fc_b[0];
    } else {
        // ==== PRODUCERS: input projections, pre-scaled into exp2 domain ====
        const int pw = (w > cons) ? (w - 1) : w;   // 0..2
        float4 wir[4], wiz[4], win[4];
        {
            const float s1 = -LOG2E, s2 = 2.0f * LOG2E;
            const float4* p0 = (const float4*)(w_ih_f + (size_t)j            * Dd);
            const float4* p1 = (const float4*)(w_ih_f + (size_t)(Hh + j)     * Dd);
            const float4* p2 = (const float4*)(w_ih_f + (size_t)(2 * Hh + j) * Dd);
#pragma unroll
            for (int q = 0; q < 4; ++q) {
                float4 a = p0[q]; wir[q] = make_float4(a.x*s1, a.y*s1, a.z*s1, a.w*s1);
                float4 c = p1[q]; wiz[q] = make_float4(c.x*s1, c.y*s1, c.z*s1, c.w*s1);
                float4 e = p2[q]; win[q] = make_float4(e.x*s2, e.y*s2, e.z*s2, e.w*s2);
            }
        }
        const float bxr = (b_ih_f[j]          + b_hh_f[j])      * (-LOG2E);
        const float bxz = (b_ih_f[Hh + j]     + b_hh_f[Hh + j]) * (-LOG2E);
        const float bxn = b_ih_f[2 * Hh + j]                    * (2.0f * LOG2E);

#define PRODUCE(C1) {                                                        \
            float4* obase = xgs4 + ((C1) & 1) * BUFSZ + j;                   \
            for (int tt = pw; tt < CH; tt += 3) {                            \
                const float4* xq = (const float4*)(xrow + (size_t)((C1) * CH + tt) * Dd); \
                float4 x0 = xq[0], x1 = xq[1], x2 = xq[2], x3 = xq[3];       \
                float ar_ = bxr + dot4(wir[0],x0) + dot4(wir[1],x1)          \
                                + dot4(wir[2],x2) + dot4(wir[3],x3);         \
                float az_ = bxz + dot4(wiz[0],x0) + dot4(wiz[1],x1)          \
                                + dot4(wiz[2],x2) + dot4(wiz[3],x3);         \
                float an_ = bxn + dot4(win[0],x0) + dot4(win[1],x1)          \
                                + dot4(win[2],x2) + dot4(win[3],x3);         \
                obase[tt * Hh] = make_float4(ar_, az_, an_, 0.0f);           \
            }                                                                \
        }

        PRODUCE(0);                       // chunk 0 before the first barrier
        for (int c = 0; c < NC; ++c) {
            lds_barrier();                // publish chunk c / consumer enters
            if (c + 1 < NC) PRODUCE(c + 1);  // fill other buffer during chunk c
        }
#undef PRODUCE
    }
}

extern "C" void kernel_launch(void* const* d_in, const int* in_sizes, int n_in,
                              void* d_out, int out_size, void* d_ws, size_t ws_size,
                              hipStream_t stream) {
    const float* x      = (const float*)d_in[0];
    const float* w_ih_f = (const float*)d_in[1];
    const float* w_hh_f = (const float*)d_in[2];
    const float* b_ih_f = (const float*)d_in[3];
    const float* b_hh_f = (const float*)d_in[4];
    const float* w_ih_b = (const float*)d_in[5];
    const float* w_hh_b = (const float*)d_in[6];
    const float* b_ih_b = (const float*)d_in[7];
    const float* b_hh_b = (const float*)d_in[8];
    const float* fc_w   = (const float*)d_in[9];
    const float* fc_b   = (const float*)d_in[10];

    bigru_pc_kernel<<<dim3(Bb), dim3(256), 0, stream>>>(
        x, w_ih_f, w_hh_f, b_ih_f, b_hh_f,
        w_ih_b, w_hh_b, b_ih_b, b_hh_b, fc_w, fc_b,
        (float*)d_out);
}